// Round 1
// 972.555 us; speedup vs baseline: 1.1654x; 1.1654x over previous
//
#include <hip/hip_runtime.h>

// GraphTransformerDecode — MFMA bf16, G3 removed via S2-decomposition.
// B=16384, P=25, D=256, H=4 (dh=64). Stage-1 softmax over 1 key == 1 -> Wk1 dead.
// Key identity: Q2p = (S2@SL)@Wq2 = S2@(SL@Wq2) = S2@SLq, so the 64-row Q2 GEMM
// and its scatter are replaced by 3-row SLq (folded into the Kg GEMM) plus
// per-channel 3-FMA expansion; scores = S2 @ (SLq.Kp^T) via one MFMA pair/wave.
// G5 split into 2x<2,4> to cap AGPRs at 32 -> 3 waves/SIMD (3 blocks/CU).

typedef __attribute__((ext_vector_type(8))) short bf16x8;  // 8 bf16 = 4 VGPRs
typedef __attribute__((ext_vector_type(4))) float f32x4;

constexpr int D   = 256;
constexpr int AST = 264;   // ubuf row stride in bf16 (16B-aligned rows)
constexpr int SST = 264;   // sbuf row stride in bf16

__device__ __forceinline__ short f2bf(float f) {
  unsigned u = __builtin_bit_cast(unsigned, f);
  u = (u + 0x7FFFu + ((u >> 16) & 1u)) >> 16;  // RNE
  return (short)u;
}
__device__ __forceinline__ float bf2f(short s) {
  unsigned u = ((unsigned)(unsigned short)s) << 16;
  return __builtin_bit_cast(float, u);
}

// ---------------- weight pre-pack: W[256x256] fp32 -> bf16 B-fragments ----------
// frag elem (nt, s, lane, j) = W[s*32 + (lane>>4)*8 + j][nt*16 + (lane&15)]
// stored at mat*65536 + ((nt*8 + s)*64 + lane)*8 + j
// mats: 0 Wq1, 1 Wv1, 2 Wo1, 3 Wq2, 4 Wk2, 5 Wv2, 6 Wo2  (3..5 contiguous -> G2')
__global__ void pack_weights(const float* __restrict__ Wq1, const float* __restrict__ Wv1,
                             const float* __restrict__ Wo1, const float* __restrict__ Wq2,
                             const float* __restrict__ Wk2, const float* __restrict__ Wv2,
                             const float* __restrict__ Wo2, short* __restrict__ ws) {
  int g = blockIdx.x * 256 + threadIdx.x;  // 7 * 8192 groups
  int mat = g >> 13, r = g & 8191;
  const float* W = (mat == 0) ? Wq1 : (mat == 1) ? Wv1 : (mat == 2) ? Wo1 :
                   (mat == 3) ? Wq2 : (mat == 4) ? Wk2 : (mat == 5) ? Wv2 : Wo2;
  int nt = r >> 9, s = (r >> 6) & 7, lane = r & 63;
  int qd = lane >> 4, mc = lane & 15;
  bf16x8 v;
#pragma unroll
  for (int j = 0; j < 8; ++j) {
    int k = s * 32 + qd * 8 + j;
    v[j] = f2bf(W[k * 256 + nt * 16 + mc]);
  }
  *reinterpret_cast<bf16x8*>(ws + (size_t)g * 8) = v;
}

// ---------------- per-wave GEMM: C = A(ubuf rows, bf16) @ B(packed) ------------
template <int MT, int NTW, bool PMODE, bool SYNCMID>
__device__ __forceinline__ void wave_gemm(const short* __restrict__ ub,
                                          const bf16x8* __restrict__ Bp, int nt0,
                                          int lane, short* __restrict__ dst,
                                          int dstStride, int lim) {
  const int m = lane & 15, q = lane >> 4;
  f32x4 acc[MT][NTW];
#pragma unroll
  for (int mt = 0; mt < MT; ++mt)
#pragma unroll
    for (int n = 0; n < NTW; ++n) acc[mt][n] = (f32x4){0.f, 0.f, 0.f, 0.f};

#pragma unroll
  for (int s = 0; s < 8; ++s) {
    bf16x8 a[MT];
#pragma unroll
    for (int mt = 0; mt < MT; ++mt)
      a[mt] = *reinterpret_cast<const bf16x8*>(ub + (mt * 16 + m) * AST + s * 32 + q * 8);
#pragma unroll
    for (int n = 0; n < NTW; ++n) {
      bf16x8 b = Bp[(nt0 + n) * 512 + s * 64 + lane];
#pragma unroll
      for (int mt = 0; mt < MT; ++mt)
        acc[mt][n] = __builtin_amdgcn_mfma_f32_16x16x32_bf16(a[mt], b, acc[mt][n], 0, 0, 0);
    }
  }
  if (SYNCMID) __syncthreads();
#pragma unroll
  for (int mt = 0; mt < MT; ++mt)
#pragma unroll
    for (int n = 0; n < NTW; ++n)
#pragma unroll
      for (int r = 0; r < 4; ++r) {
        int rr = mt * 16 + q * 4 + r;
        bool ok = PMODE ? ((rr & 31) < 25) : (rr < lim);
        if (ok) dst[rr * dstStride + (nt0 + n) * 16 + m] = f2bf(acc[mt][n][r]);
      }
}

// ------------- G2' GEMM: A rows {SL(0..5), Kg(6..11)} @ [Wq2|Wk2|Wv2] ----------
// Compact scatter: mat0 valid rr 0..5 -> sbuf rows 0..5 (SLq)
//                  mat1 valid rr 6..11 -> sbuf rows 6..11 (Kp)
//                  mat2 valid rr 6..11 -> sbuf rows 12..17 (Vp)
__device__ __forceinline__ void gemm_qkv(const short* __restrict__ ub,
                                         const bf16x8* __restrict__ Bp, int nt0,
                                         int lane, short* __restrict__ sb) {
  const int m = lane & 15, q = lane >> 4;
  f32x4 acc[12];
#pragma unroll
  for (int n = 0; n < 12; ++n) acc[n] = (f32x4){0.f, 0.f, 0.f, 0.f};
#pragma unroll
  for (int s = 0; s < 8; ++s) {
    bf16x8 a = *reinterpret_cast<const bf16x8*>(ub + m * AST + s * 32 + q * 8);
#pragma unroll
    for (int n = 0; n < 12; ++n) {
      bf16x8 b = Bp[(nt0 + n) * 512 + s * 64 + lane];
      acc[n] = __builtin_amdgcn_mfma_f32_16x16x32_bf16(a, b, acc[n], 0, 0, 0);
    }
  }
#pragma unroll
  for (int n = 0; n < 12; ++n) {
    int nt = nt0 + n;
    int mat = nt >> 4;
    int lo = (mat == 0) ? 0 : 6;
    int col = (nt & 15) * 16 + m;
#pragma unroll
    for (int r = 0; r < 4; ++r) {
      int rr = q * 4 + r;
      if (rr >= lo && rr < lo + 6)
        sb[(mat * 6 + rr - lo) * SST + col] = f2bf(acc[n][r]);
    }
  }
}

// ---------------- small layernorm (6 rows, shuffle + cross-wave) ---------------
__device__ __forceinline__ void ln6(float (&v)[2][3], const float* __restrict__ g,
                                    const float* __restrict__ b, int tid, float* red) {
  const int lane = tid & 63, wv = tid >> 6;
#pragma unroll
  for (int i = 0; i < 6; ++i) {
    float x = v[i / 3][i % 3];
    float s = x, qq = x * x;
#pragma unroll
    for (int mm = 32; mm; mm >>= 1) {
      s += __shfl_xor(s, mm, 64);
      qq += __shfl_xor(qq, mm, 64);
    }
    if (lane == 0) {
      red[(i * 4 + wv) * 2 + 0] = s;
      red[(i * 4 + wv) * 2 + 1] = qq;
    }
  }
  __syncthreads();
  const float gg = g[tid], bb = b[tid];
#pragma unroll
  for (int i = 0; i < 6; ++i) {
    float s = red[(i * 4 + 0) * 2] + red[(i * 4 + 1) * 2] +
              red[(i * 4 + 2) * 2] + red[(i * 4 + 3) * 2];
    float qq = red[(i * 4 + 0) * 2 + 1] + red[(i * 4 + 1) * 2 + 1] +
               red[(i * 4 + 2) * 2 + 1] + red[(i * 4 + 3) * 2 + 1];
    float mean = s * (1.0f / 256.0f);
    float var  = qq * (1.0f / 256.0f) - mean * mean;
    float inv  = rsqrtf(var + 1e-5f);
    float x = v[i / 3][i % 3];
    v[i / 3][i % 3] = (x - mean) * inv * gg + bb;
  }
  __syncthreads();
}

// ---------------- cooperative row stats over ubuf (64 rows bf16) ---------------
__device__ __forceinline__ void coop_stats(const short* __restrict__ ub, int tid,
                                           float* red, float (*st)[2]) {
  const int rr = tid >> 2, part = tid & 3;
  float s = 0.f, ss = 0.f;
  if ((rr & 31) < 25) {
#pragma unroll
    for (int c = 0; c < 8; ++c) {
      bf16x8 v8 = *reinterpret_cast<const bf16x8*>(ub + rr * AST + part * 64 + c * 8);
#pragma unroll
      for (int j = 0; j < 8; ++j) {
        float f = bf2f(v8[j]);
        s += f;
        ss = fmaf(f, f, ss);
      }
    }
  }
  red[(rr * 4 + part) * 2 + 0] = s;
  red[(rr * 4 + part) * 2 + 1] = ss;
  __syncthreads();
  if (tid < 64) {
    float S = 0.f, SS = 0.f;
#pragma unroll
    for (int i = 0; i < 4; ++i) {
      S  += red[(tid * 4 + i) * 2 + 0];
      SS += red[(tid * 4 + i) * 2 + 1];
    }
    float mean = S * (1.0f / 256.0f);
    float var  = SS * (1.0f / 256.0f) - mean * mean;
    st[tid][0] = mean;
    st[tid][1] = rsqrtf(var + 1e-5f);
  }
}

// ---------------------------------- main ---------------------------------------
__global__ __launch_bounds__(256, 3)
void gt_mfma(const float* __restrict__ X, const float* __restrict__ S1,
             const float* __restrict__ S2, const float* __restrict__ adj1,
             const float* __restrict__ adj2,
             const float* __restrict__ g11, const float* __restrict__ b11,
             const float* __restrict__ g12, const float* __restrict__ b12,
             const float* __restrict__ g21, const float* __restrict__ b21,
             const float* __restrict__ g22, const float* __restrict__ b22,
             const short* __restrict__ wsp, float* __restrict__ out) {
  __shared__ __align__(16) short ubuf[64 * AST];   // A tiles / x,O,O2 scatter
  __shared__ __align__(16) short sbuf[18 * SST];   // SLq(0..5) Kp(6..11) Vp(12..17)
                                                   // stage-1: robuf rows 0..5; qv alias rows 6..9
  __shared__ __align__(16) float wbuf[4][64][4];   // softmax weights per head
  __shared__ float slkbuf[4][6][3];                // SLK per head (scaled)
  __shared__ float stbuf[64][2];                   // row mean / inv
  __shared__ float redbuf[512];                    // reduction scratch

  const int tid = threadIdx.x, lane = tid & 63, wv = tid >> 6;
  const int b0 = blockIdx.x * 2;

  const bf16x8* pQV1 = (const bf16x8*)(wsp + 0 * 65536);  // [Wq1|Wv1], nt 0..31
  const bf16x8* pWo1 = (const bf16x8*)(wsp + 2 * 65536);
  const bf16x8* pQKV = (const bf16x8*)(wsp + 3 * 65536);  // [Wq2|Wk2|Wv2], nt 0..47
  const bf16x8* pWo2 = (const bf16x8*)(wsp + 6 * 65536);

  short* qv = sbuf + 6 * SST;  // alias: 2 rows x 512 (stride 528) for G1 output

  // ---- phase 0: A1 = X rows (2). Pad rows stay garbage: all GEMM outputs from
  // pad rows are masked at scatter, and MFMA rows are independent. ----
  float x0 = X[(size_t)(b0 + 0) * D + tid];
  float x1 = X[(size_t)(b0 + 1) * D + tid];
  ubuf[0 * AST + tid] = f2bf(x0);
  ubuf[1 * AST + tid] = f2bf(x1);
  __syncthreads();

  // ---- G1: [X] @ [Wq1|Wv1] -> qv rows {b}, cols 0..511 ----
  wave_gemm<1, 8, false, false>(ubuf, pQV1, wv * 8, lane, qv, 528, 2);
  __syncthreads();

  const float a1 = adj1[0];
  float o1[2][3];
#pragma unroll
  for (int b = 0; b < 2; ++b) {
    float xq = bf2f(qv[b * 528 + tid]);
    float xv = bf2f(qv[b * 528 + 256 + tid]) * a1;
#pragma unroll
    for (int qq = 0; qq < 3; ++qq) o1[b][qq] = fmaf(S1[qq], xq, xv);
  }
  ln6(o1, g11, b11, tid, redbuf);

  // ---- G2: O1 @ Wo1 -> sbuf rows {b*3+q} cols 0..255 ----
#pragma unroll
  for (int b = 0; b < 2; ++b)
#pragma unroll
    for (int qq = 0; qq < 3; ++qq) ubuf[(b * 3 + qq) * AST + tid] = f2bf(o1[b][qq]);
  __syncthreads();
  wave_gemm<1, 4, false, false>(ubuf, pWo1, wv * 4, lane, sbuf, SST, 6);
  __syncthreads();
#pragma unroll
  for (int b = 0; b < 2; ++b)
#pragma unroll
    for (int qq = 0; qq < 3; ++qq)
      o1[b][qq] += fmaxf(bf2f(sbuf[(b * 3 + qq) * SST + tid]), 0.f);
  ln6(o1, g12, b12, tid, redbuf);  // o1 = scale_liner channel tid

  // ---- A2 rows: SL (0..5), Kg = adj2@SL (6..11) ----
#pragma unroll
  for (int b = 0; b < 2; ++b)
#pragma unroll
    for (int qq = 0; qq < 3; ++qq) ubuf[(b * 3 + qq) * AST + tid] = f2bf(o1[b][qq]);
#pragma unroll
  for (int b = 0; b < 2; ++b)
#pragma unroll
    for (int i = 0; i < 3; ++i) {
      float kg = adj2[i * 3 + 0] * o1[b][0] + adj2[i * 3 + 1] * o1[b][1] +
                 adj2[i * 3 + 2] * o1[b][2];
      ubuf[(6 + b * 3 + i) * AST + tid] = f2bf(kg);
    }
  __syncthreads();

  // ---- G2': {SL|Kg} @ [Wq2|Wk2|Wv2] -> sbuf SLq/Kp/Vp ----
  gemm_qkv(ubuf, pQKV, wv * 12, lane, sbuf);
  __syncthreads();

  // ---- scores: SLK = SLq.Kp^T per head (1 MFMA pair/wave), then
  //      w[p][k] = softmax_k( S2[p] @ SLK * 1/16 ) ----
  {
    const int m = lane & 15, q = lane >> 4;
    f32x4 sa = (f32x4){0.f, 0.f, 0.f, 0.f};
#pragma unroll
    for (int s = 0; s < 2; ++s) {
      bf16x8 aq = *reinterpret_cast<const bf16x8*>(
          sbuf + m * SST + wv * 64 + s * 32 + q * 8);
      bf16x8 bk = (bf16x8){0, 0, 0, 0, 0, 0, 0, 0};
      if (m < 6)
        bk = *reinterpret_cast<const bf16x8*>(
            sbuf + (6 + m) * SST + wv * 64 + s * 32 + q * 8);
      sa = __builtin_amdgcn_mfma_f32_16x16x32_bf16(aq, bk, sa, 0, 0, 0);
    }
#pragma unroll
    for (int r = 0; r < 4; ++r) {
      int i = q * 4 + r;
      if (i < 6 && m < 6 && ((i >= 3) == (m >= 3)))
        slkbuf[wv][i][m % 3] = sa[r] * 0.0625f;  // 1/sqrt(256) folded here
    }
    // same-wave DS ordering: writes above complete before reads below
    int b = lane >> 5, p = lane & 31;
    if (p < 25) {
      float sc0 = 0.f, sc1 = 0.f, sc2 = 0.f;
#pragma unroll
      for (int ii = 0; ii < 3; ++ii) {
        float s2v = S2[p * 3 + ii];
        sc0 = fmaf(s2v, slkbuf[wv][b * 3 + ii][0], sc0);
        sc1 = fmaf(s2v, slkbuf[wv][b * 3 + ii][1], sc1);
        sc2 = fmaf(s2v, slkbuf[wv][b * 3 + ii][2], sc2);
      }
      float mx = fmaxf(sc0, fmaxf(sc1, sc2));
      float e0 = __expf(sc0 - mx), e1 = __expf(sc1 - mx), e2 = __expf(sc2 - mx);
      float inv = 1.f / (e0 + e1 + e2);
      wbuf[wv][b * 32 + p][0] = e0 * inv;
      wbuf[wv][b * 32 + p][1] = e1 * inv;
      wbuf[wv][b * 32 + p][2] = e2 * inv;
      wbuf[wv][b * 32 + p][3] = 0.f;
    }
  }
  __syncthreads();

  // ---- attention apply + residual: x = S2@SLq + w@Vp (head of channel tid == wv) ----
  float accv[2][25];
#pragma unroll
  for (int b = 0; b < 2; ++b) {
    float slq0 = bf2f(sbuf[(b * 3 + 0) * SST + tid]);
    float slq1 = bf2f(sbuf[(b * 3 + 1) * SST + tid]);
    float slq2 = bf2f(sbuf[(b * 3 + 2) * SST + tid]);
    float vp0 = bf2f(sbuf[(12 + b * 3 + 0) * SST + tid]);
    float vp1 = bf2f(sbuf[(12 + b * 3 + 1) * SST + tid]);
    float vp2 = bf2f(sbuf[(12 + b * 3 + 2) * SST + tid]);
#pragma unroll
    for (int p = 0; p < 25; ++p) {
      float4 w4 = *reinterpret_cast<const float4*>(&wbuf[wv][b * 32 + p][0]);
      float qpv = S2[p * 3 + 0] * slq0 + S2[p * 3 + 1] * slq1 + S2[p * 3 + 2] * slq2;
      float x = qpv + w4.x * vp0 + w4.y * vp1 + w4.z * vp2;
      accv[b][p] = x;
      ubuf[(b * 32 + p) * AST + tid] = f2bf(x);
    }
  }
  __syncthreads();

  // ---- LN21 (cooperative stats) ----
  coop_stats(ubuf, tid, redbuf, stbuf);
  __syncthreads();
  {
    const float gg = g21[tid], bb2 = b21[tid];
#pragma unroll
    for (int b = 0; b < 2; ++b)
#pragma unroll
      for (int p = 0; p < 25; ++p) {
        int rr = b * 32 + p;
        accv[b][p] = (accv[b][p] - stbuf[rr][0]) * stbuf[rr][1] * gg + bb2;
      }
  }

  // ---- A5 = normalized O, G5: O @ Wo2 -> ubuf (split per batch: acc 32 regs) ----
#pragma unroll
  for (int b = 0; b < 2; ++b)
#pragma unroll
    for (int p = 0; p < 25; ++p) ubuf[(b * 32 + p) * AST + tid] = f2bf(accv[b][p]);
  __syncthreads();
  wave_gemm<2, 4, true, true>(ubuf, pWo2, wv * 4, lane, ubuf, AST, 0);
  wave_gemm<2, 4, true, true>(ubuf + 32 * AST, pWo2, wv * 4, lane, ubuf + 32 * AST, AST, 0);
  __syncthreads();

  // ---- O += relu(O@Wo2); LN22; store ----
#pragma unroll
  for (int b = 0; b < 2; ++b)
#pragma unroll
    for (int p = 0; p < 25; ++p) {
      float r = bf2f(ubuf[(b * 32 + p) * AST + tid]);
      float x = accv[b][p] + fmaxf(r, 0.f);
      accv[b][p] = x;
      ubuf[(b * 32 + p) * AST + tid] = f2bf(x);
    }
  __syncthreads();
  coop_stats(ubuf, tid, redbuf, stbuf);
  __syncthreads();
  {
    const float gg = g22[tid], bb2 = b22[tid];
#pragma unroll
    for (int b = 0; b < 2; ++b)
#pragma unroll
      for (int p = 0; p < 25; ++p) {
        int rr = b * 32 + p;
        float v = (accv[b][p] - stbuf[rr][0]) * stbuf[rr][1] * gg + bb2;
        out[((size_t)(b0 + b) * 25 + p) * D + tid] = v;
      }
  }
}

extern "C" void kernel_launch(void* const* d_in, const int* in_sizes, int n_in,
                              void* d_out, int out_size, void* d_ws, size_t ws_size,
                              hipStream_t stream) {
  const float* X    = (const float*)d_in[0];
  const float* S1   = (const float*)d_in[1];
  const float* S2   = (const float*)d_in[2];
  const float* adj1 = (const float*)d_in[3];
  const float* adj2 = (const float*)d_in[4];
  const float* Wq1  = (const float*)d_in[5];
  // d_in[6] = Wk1: dead (stage-1 softmax over one key == 1)
  const float* Wv1  = (const float*)d_in[7];
  const float* Wo1  = (const float*)d_in[8];
  const float* g11  = (const float*)d_in[9];
  const float* b11  = (const float*)d_in[10];
  const float* g12  = (const float*)d_in[11];
  const float* b12  = (const float*)d_in[12];
  const float* Wq2  = (const float*)d_in[13];
  const float* Wk2  = (const float*)d_in[14];
  const float* Wv2  = (const float*)d_in[15];
  const float* Wo2  = (const float*)d_in[16];
  const float* g21  = (const float*)d_in[17];
  const float* b21  = (const float*)d_in[18];
  const float* g22  = (const float*)d_in[19];
  const float* b22  = (const float*)d_in[20];

  short* wsp = (short*)d_ws;  // needs 7*65536*2 = 917504 bytes

  // re-pack weights every launch (d_ws is re-poisoned before each timed call)
  hipLaunchKernelGGL(pack_weights, dim3(224), dim3(256), 0, stream,
                     Wq1, Wv1, Wo1, Wq2, Wk2, Wv2, Wo2, wsp);

  const int B = in_sizes[0] / D;  // X is [B,1,D]
  hipLaunchKernelGGL(gt_mfma, dim3(B / 2), dim3(256), 0, stream,
                     X, S1, S2, adj1, adj2, g11, b11, g12, b12,
                     g21, b21, g22, b22, (const short*)wsp, (float*)d_out);
}